// Round 15
// baseline (747.821 us; speedup 1.0000x reference)
//
#include <hip/hip_runtime.h>
#include <hip/hip_fp16.h>

// GCN: 3x (GEMM -> normalized adjacency aggregate) + mean-pool + MLP.
// R2 scatter->CSR+gather. R6 hs fp16 (419). R7 col-part fill (409).
// R8 fp16 MFMA GEMM (345). R9 pool split (341). R11 fp16 gather out (338).
// R14 fixed-capacity bucket fill replaces deg+scan+fill; 9 dispatches (288).
// R10/R12/R13 lessons: no intra-row gather slicing (line-granular), no
//   grid.sync mega-kernel, no LDS-heavy gather fusion (occupancy).
// R15: (a) fused_gpool rebuilt with 2 half-wave edge streams x 8-deep unroll
//      (16 outstanding 4B row-loads/wave, was 8) + bigger grid;
//      (b) mlp folded into fused_gpool via last-block pattern (threadfence +
//      done-counter; atomic reads of pooled; shfl-broadcast dots). 8 dispatches.
//   out[c] = dinv[c] * ( hs[c] + sum_{(r->c)} hs[r] ),  hs = (X@W) * dinv[row]

#define NGRAPH 100
#define CAP 64           // bucket slots per node

typedef _Float16 f16x8 __attribute__((ext_vector_type(8)));
typedef float f32x4 __attribute__((ext_vector_type(4)));

// ---------------- prep: Wt transpose-to-fp16 + zero cnt/pooled/done ----------------

__global__ __launch_bounds__(256) void prep_all(const float* __restrict__ W1,
                                                const float* __restrict__ W2,
                                                const float* __restrict__ W3,
                                                __half* __restrict__ Wt1,
                                                __half* __restrict__ Wt2,
                                                __half* __restrict__ Wt3,
                                                int* __restrict__ cnt,
                                                float* __restrict__ pooled,
                                                int* __restrict__ done, int n) {
    const int idx = blockIdx.x * 256 + threadIdx.x;    // 256 blocks = 65536 thr
    if (idx < 16384) {
        int nn = idx >> 7, k = idx & 127;
        Wt1[idx] = __float2half(W1[k * 128 + nn]);
    } else if (idx < 32768) {
        int j = idx - 16384;
        int nn = j >> 7, k = j & 127;
        Wt2[j] = __float2half(W2[k * 128 + nn]);
    } else if (idx < 40960) {
        int j = idx - 32768;
        int nn = j >> 7, k = j & 127;
        Wt3[j] = __float2half(W3[k * 64 + nn]);
    }
    if (idx < n) cnt[idx] = 0;                          // 65536 >= n
    if (idx < NGRAPH * 64) pooled[idx] = 0.0f;
    if (idx == 0) *done = 0;
}

// ---------------- bucket fill, col-partitioned (deg+scan+fill in one) ----------

__global__ void fill_bucket(const int* __restrict__ row, const int* __restrict__ col,
                            int* __restrict__ cnt, int* __restrict__ bucket,
                            int E, int colsPerGroup) {
    const int g  = blockIdx.x & 7;
    const int gb = blockIdx.x >> 3;
    const int nb = gridDim.x >> 3;
    const int lo = g * colsPerGroup, hi = lo + colsPerGroup;
    for (int e = gb * 256 + threadIdx.x; e < E; e += nb * 256) {
        int c = col[e];
        if (c >= lo && c < hi) {
            int pos = atomicAdd(&cnt[c], 1);
            bucket[c * CAP + pos] = row[e];
        }
    }
}

// ---------------- MFMA GEMM: Yh(fp16) = relu?(X + b) @ W * dinv[row] ----------

template <int OUT, bool F16IN>
__global__ __launch_bounds__(256) void gemm_mfma(const void* __restrict__ Xv,
                                                 const __half* __restrict__ Wt,
                                                 const float* __restrict__ bias_in,
                                                 const int* __restrict__ cnt,
                                                 __half* __restrict__ Yh, int n) {
    __shared__ _Float16 Xs[64 * 128];
    __shared__ _Float16 Ws[OUT * 128];
    __shared__ float bs[128];

    const float*  Xf = (const float*)Xv;
    const __half* Xh = (const __half*)Xv;

    const int t = threadIdx.x;
    if (t < 128) bs[t] = (bias_in != nullptr) ? bias_in[t] : 0.0f;
    __syncthreads();

    const int row0 = blockIdx.x * 64;
    const bool do_relu = (bias_in != nullptr);

    for (int c = t; c < 64 * 16; c += 256) {
        const int r = c >> 4, q = c & 15;
        const int gr = row0 + r;
        float vals[8];
        #pragma unroll
        for (int i = 0; i < 8; ++i) vals[i] = 0.0f;
        if (gr < n) {
            if (F16IN) {
                f16x8 hv = *(const f16x8*)&Xh[(size_t)gr * 128 + q * 8];
                #pragma unroll
                for (int i = 0; i < 8; ++i) vals[i] = (float)hv[i];
            } else {
                float4 va = *(const float4*)&Xf[(size_t)gr * 128 + q * 8];
                float4 vb = *(const float4*)&Xf[(size_t)gr * 128 + q * 8 + 4];
                vals[0] = va.x; vals[1] = va.y; vals[2] = va.z; vals[3] = va.w;
                vals[4] = vb.x; vals[5] = vb.y; vals[6] = vb.z; vals[7] = vb.w;
            }
        }
        if (do_relu) {
            const int k = q * 8;
            #pragma unroll
            for (int i = 0; i < 8; ++i) vals[i] = fmaxf(vals[i] + bs[k + i], 0.f);
        }
        f16x8 hv;
        #pragma unroll
        for (int i = 0; i < 8; ++i) hv[i] = (_Float16)vals[i];
        *(f16x8*)&Xs[(size_t)((r << 4) + (q ^ (r & 15))) * 8] = hv;
    }
    for (int c = t; c < OUT * 16; c += 256) {
        const int nn = c >> 4, q = c & 15;
        f16x8 w = *(const f16x8*)&Wt[nn * 128 + q * 8];
        *(f16x8*)&Ws[(size_t)((nn << 4) + (q ^ (nn & 15))) * 8] = w;
    }
    __syncthreads();

    constexpr int NT = OUT / 16;
    const int lane = t & 63, wave = t >> 6;
    const int m = lane & 15, quad = lane >> 4;

    f32x4 acc[NT];
    #pragma unroll
    for (int i = 0; i < NT; ++i) acc[i] = (f32x4){0.f, 0.f, 0.f, 0.f};

    #pragma unroll
    for (int s = 0; s < 4; ++s) {
        const int qa = s * 4 + quad;
        f16x8 a = *(const f16x8*)&Xs[(size_t)(((wave * 16 + m) << 4) + (qa ^ m)) * 8];
        #pragma unroll
        for (int tt = 0; tt < NT; ++tt) {
            f16x8 b = *(const f16x8*)&Ws[(size_t)(((tt * 16 + m) << 4) + (qa ^ m)) * 8];
            acc[tt] = __builtin_amdgcn_mfma_f32_16x16x32_f16(a, b, acc[tt], 0, 0, 0);
        }
    }

    #pragma unroll
    for (int i = 0; i < 4; ++i) {
        const int gr = row0 + wave * 16 + quad * 4 + i;
        if (gr < n) {
            const float dw = 1.0f / sqrtf((float)(cnt[gr] + 1));
            #pragma unroll
            for (int tt = 0; tt < NT; ++tt)
                Yh[(size_t)gr * OUT + tt * 16 + m] = __float2half(acc[tt][i] * dw);
        }
    }
}

// ---------------- gather<128> (bucket-based): fp16 in/out, fp32 accum ----------------

template <int F>
__global__ void gather_kernel(const __half* __restrict__ hs, const int* __restrict__ cnt,
                              const int* __restrict__ bucket,
                              __half* __restrict__ outh, int n) {
    const int lane = threadIdx.x & 63;
    const int c = (blockIdx.x * blockDim.x + threadIdx.x) >> 6;
    if (c >= n) return;
    const int beg = c * CAP;
    const int end = beg + cnt[c];
    const float w = 1.0f / sqrtf((float)(cnt[c] + 1));
    const float2* hq = (const float2*)hs;

    auto cvt = [](float2 raw) {
        __half2 ha = *(__half2*)&raw.x;
        __half2 hb = *(__half2*)&raw.y;
        float2 fa = __half22float2(ha);
        float2 fb = __half22float2(hb);
        return make_float4(fa.x, fa.y, fb.x, fb.y);
    };
    auto pack = [](float4 v) {
        float2 o;
        *(__half2*)&o.x = __float22half2_rn(make_float2(v.x, v.y));
        *(__half2*)&o.y = __float22half2_rn(make_float2(v.z, v.w));
        return o;
    };

    if (F == 128) {
        const int half = lane >> 5;
        const int l    = lane & 31;
        float4 acc = make_float4(0.f, 0.f, 0.f, 0.f);
        if (half == 0) acc = cvt(hq[(size_t)c * 32 + l]);
        int j = beg + half;
        for (; j + 6 < end; j += 8) {
            int s0 = bucket[j], s1 = bucket[j + 2], s2 = bucket[j + 4], s3 = bucket[j + 6];
            float4 v0 = cvt(hq[(size_t)s0 * 32 + l]);
            float4 v1 = cvt(hq[(size_t)s1 * 32 + l]);
            float4 v2 = cvt(hq[(size_t)s2 * 32 + l]);
            float4 v3 = cvt(hq[(size_t)s3 * 32 + l]);
            acc.x += v0.x + v1.x + v2.x + v3.x;
            acc.y += v0.y + v1.y + v2.y + v3.y;
            acc.z += v0.z + v1.z + v2.z + v3.z;
            acc.w += v0.w + v1.w + v2.w + v3.w;
        }
        for (; j < end; j += 2) {
            float4 v = cvt(hq[(size_t)bucket[j] * 32 + l]);
            acc.x += v.x; acc.y += v.y; acc.z += v.z; acc.w += v.w;
        }
        acc.x += __shfl(acc.x, lane ^ 32);
        acc.y += __shfl(acc.y, lane ^ 32);
        acc.z += __shfl(acc.z, lane ^ 32);
        acc.w += __shfl(acc.w, lane ^ 32);
        if (half == 0) {
            float4 o = make_float4(w * acc.x, w * acc.y, w * acc.z, w * acc.w);
            *(float2*)&outh[(size_t)c * 128 + l * 4] = pack(o);
        }
    } else {     // F == 64 (unused this round; kept for completeness)
        const int q = lane >> 4;
        const int l = lane & 15;
        float4 acc = make_float4(0.f, 0.f, 0.f, 0.f);
        if (q == 0) acc = cvt(hq[(size_t)c * 16 + l]);
        int j = beg + q;
        for (; j + 12 < end; j += 16) {
            int s0 = bucket[j], s1 = bucket[j + 4], s2 = bucket[j + 8], s3 = bucket[j + 12];
            float4 v0 = cvt(hq[(size_t)s0 * 16 + l]);
            float4 v1 = cvt(hq[(size_t)s1 * 16 + l]);
            float4 v2 = cvt(hq[(size_t)s2 * 16 + l]);
            float4 v3 = cvt(hq[(size_t)s3 * 16 + l]);
            acc.x += v0.x + v1.x + v2.x + v3.x;
            acc.y += v0.y + v1.y + v2.y + v3.y;
            acc.z += v0.z + v1.z + v2.z + v3.z;
            acc.w += v0.w + v1.w + v2.w + v3.w;
        }
        for (; j < end; j += 4) {
            float4 v = cvt(hq[(size_t)bucket[j] * 16 + l]);
            acc.x += v.x; acc.y += v.y; acc.z += v.z; acc.w += v.w;
        }
        acc.x += __shfl(acc.x, lane ^ 16);
        acc.y += __shfl(acc.y, lane ^ 16);
        acc.z += __shfl(acc.z, lane ^ 16);
        acc.w += __shfl(acc.w, lane ^ 16);
        acc.x += __shfl(acc.x, lane ^ 32);
        acc.y += __shfl(acc.y, lane ^ 32);
        acc.z += __shfl(acc.z, lane ^ 32);
        acc.w += __shfl(acc.w, lane ^ 32);
        if (q == 0) {
            float4 o = make_float4(w * acc.x, w * acc.y, w * acc.z, w * acc.w);
            *(float2*)&outh[(size_t)c * 64 + l * 4] = pack(o);
        }
    }
}

// ---------------- fused gather(64) + pool + (last block) MLP ----------------
// 2 half-wave edge streams per node: 32 lanes x dword (2 fp16) = full 128B row,
// 8-deep unroll per stream -> 16 outstanding loads/wave. shfl xor32 combine.
// Boundary-flush atomics (batch sorted). Last finished block runs the MLP head
// (shfl-broadcast dots, atomic reads of pooled for coherence).

__global__ __launch_bounds__(256) void fused_gpool(const __half* __restrict__ hs,
                                                   const int* __restrict__ cnt,
                                                   const int* __restrict__ bucket,
                                                   const float* __restrict__ b3,
                                                   const int* __restrict__ batch,
                                                   float* __restrict__ pooled,
                                                   const float* __restrict__ Wf1,
                                                   const float* __restrict__ bf1,
                                                   const float* __restrict__ Wf2,
                                                   const float* __restrict__ bf2,
                                                   float* __restrict__ out,
                                                   int* __restrict__ done, int n) {
    const int lane  = threadIdx.x & 63;
    const int half  = lane >> 5;               // edge stream id
    const int li    = lane & 31;               // dword index in 64-feat row
    const int wave  = (blockIdx.x * blockDim.x + threadIdx.x) >> 6;
    const int nwav  = (gridDim.x * blockDim.x) >> 6;
    const int chunk = (n + nwav - 1) / nwav;
    const int beg = wave * chunk;
    const int end = min(beg + chunk, n);
    const unsigned* h2 = (const unsigned*)hs;  // row = 32 dwords

    auto cvt2 = [](unsigned raw) { return __half22float2(*(__half2*)&raw); };

    if (beg < end) {
        const float bias0 = b3[li * 2], bias1 = b3[li * 2 + 1];
        int curg = batch[beg];
        float2 acc = make_float2(0.f, 0.f);
        for (int i = beg; i < end; ++i) {
            int g = batch[i];                  // wave-uniform
            if (g != curg) {
                if (half == 0) {
                    atomicAdd(&pooled[curg * 64 + li * 2],     acc.x);
                    atomicAdd(&pooled[curg * 64 + li * 2 + 1], acc.y);
                }
                acc = make_float2(0.f, 0.f); curg = g;
            }
            const int deg = cnt[i];
            const float dv = 1.0f / sqrtf((float)(deg + 1));
            float2 sv = make_float2(0.f, 0.f);
            if (half == 0) sv = cvt2(h2[(size_t)i * 32 + li]);   // self-loop
            const int eb = i * CAP, ee = eb + deg;
            int j = eb + half;
            for (; j + 14 < ee; j += 16) {     // 8-deep per stream
                int a0 = bucket[j],      a1 = bucket[j + 2],  a2 = bucket[j + 4],  a3 = bucket[j + 6];
                int a4 = bucket[j + 8],  a5 = bucket[j + 10], a6 = bucket[j + 12], a7 = bucket[j + 14];
                float2 v0 = cvt2(h2[(size_t)a0 * 32 + li]);
                float2 v1 = cvt2(h2[(size_t)a1 * 32 + li]);
                float2 v2 = cvt2(h2[(size_t)a2 * 32 + li]);
                float2 v3 = cvt2(h2[(size_t)a3 * 32 + li]);
                float2 v4 = cvt2(h2[(size_t)a4 * 32 + li]);
                float2 v5 = cvt2(h2[(size_t)a5 * 32 + li]);
                float2 v6 = cvt2(h2[(size_t)a6 * 32 + li]);
                float2 v7 = cvt2(h2[(size_t)a7 * 32 + li]);
                sv.x += (v0.x + v1.x) + (v2.x + v3.x) + (v4.x + v5.x) + (v6.x + v7.x);
                sv.y += (v0.y + v1.y) + (v2.y + v3.y) + (v4.y + v5.y) + (v6.y + v7.y);
            }
            for (; j < ee; j += 2) {
                float2 v = cvt2(h2[(size_t)bucket[j] * 32 + li]);
                sv.x += v.x; sv.y += v.y;
            }
            sv.x += __shfl(sv.x, lane ^ 32);   // combine streams
            sv.y += __shfl(sv.y, lane ^ 32);
            acc.x += fmaxf(dv * sv.x + bias0, 0.f);
            acc.y += fmaxf(dv * sv.y + bias1, 0.f);
        }
        if (half == 0) {
            atomicAdd(&pooled[curg * 64 + li * 2],     acc.x);
            atomicAdd(&pooled[curg * 64 + li * 2 + 1], acc.y);
        }
    }

    // ---- last-block MLP head ----
    __shared__ int lastFlag;
    __threadfence();
    __syncthreads();
    if (threadIdx.x == 0) {
        int d = atomicAdd(done, 1);
        lastFlag = (d == (int)gridDim.x - 1) ? 1 : 0;
    }
    __syncthreads();
    if (!lastFlag) return;

    const int w4 = threadIdx.x >> 6;           // 4 waves x 25 graphs
    for (int g = w4 * 25; g < w4 * 25 + 25; ++g) {
        // node count of graph g (all lanes redundantly)
        int lo = 0, hi = n;
        while (lo < hi) { int mid = (lo + hi) >> 1; if (batch[mid] < g) lo = mid + 1; else hi = mid; }
        const int s0 = lo;
        lo = 0; hi = n;
        while (lo < hi) { int mid = (lo + hi) >> 1; if (batch[mid] < g + 1) lo = mid + 1; else hi = mid; }
        const int cg = lo - s0;
        // coherent read of pooled (atomic, matches producer scope)
        float pm = atomicAdd(&pooled[g * 64 + lane], 0.0f) / (float)(cg > 0 ? cg : 1);
        // hid = relu(bf1 + pm @ Wf1)  [lanes 0..31]
        float a = (lane < 32) ? bf1[lane] : 0.f;
        #pragma unroll
        for (int k = 0; k < 64; ++k) {
            float pk = __shfl(pm, k);
            if (lane < 32) a += pk * Wf1[k * 32 + lane];
        }
        float h = fmaxf(a, 0.f);
        // out = bf2 + hid @ Wf2  [lanes 0..9]
        float o = (lane < 10) ? bf2[lane] : 0.f;
        #pragma unroll
        for (int k = 0; k < 32; ++k) {
            float hk = __shfl(h, k);
            if (lane < 10) o += hk * Wf2[k * 10 + lane];
        }
        if (lane < 10) out[g * 10 + lane] = o;
    }
}

// ---------------- launcher ----------------

extern "C" void kernel_launch(void* const* d_in, const int* in_sizes, int n_in,
                              void* d_out, int out_size, void* d_ws, size_t ws_size,
                              hipStream_t stream) {
    const float* x     = (const float*)d_in[0];
    const int*   edge  = (const int*)  d_in[1];
    const int*   batch = (const int*)  d_in[2];
    const float* W1    = (const float*)d_in[3];
    const float* b1    = (const float*)d_in[4];
    const float* W2    = (const float*)d_in[5];
    const float* b2    = (const float*)d_in[6];
    const float* W3    = (const float*)d_in[7];
    const float* b3    = (const float*)d_in[8];
    const float* Wf1   = (const float*)d_in[9];
    const float* bf1   = (const float*)d_in[10];
    const float* Wf2   = (const float*)d_in[11];
    const float* bf2   = (const float*)d_in[12];
    float* out = (float*)d_out;

    const int E = in_sizes[1] / 2;     // 800000
    const int n = in_sizes[2];         // 50000
    const int* row = edge;
    const int* col = edge + E;

    const int colsPerGroup = (n + 7) / 8;                  // 6250

    const size_t n_pad = ((size_t)n + 64) & ~(size_t)63;
    char* wsb = (char*)d_ws;
    int*    cnt    = (int*)wsb;                  wsb += n_pad * 4;            // degree
    float*  pooled = (float*)wsb;                wsb += NGRAPH * 64 * 4;
    int*    done   = (int*)wsb;                  wsb += 64 * 4;
    int*    bucket = (int*)wsb;                  wsb += (size_t)n_pad * CAP * 4;  // 12.8 MB
    __half* Wt1    = (__half*)wsb;               wsb += 16384 * 2;
    __half* Wt2    = (__half*)wsb;               wsb += 16384 * 2;
    __half* Wt3    = (__half*)wsb;               wsb += 8192 * 2;
    __half* bufA   = (__half*)wsb;               wsb += (size_t)n * 128 * 2;  // 12.8 MB
    __half* bufB   = (__half*)wsb;                                            // 12.8 MB

    // ---- prep + bucket build ----
    prep_all<<<256, 256, 0, stream>>>(W1, W2, W3, Wt1, Wt2, Wt3, cnt, pooled, done, n);
    fill_bucket<<<1024, 256, 0, stream>>>(row, col, cnt, bucket, E, colsPerGroup);

    const int ggemm = (n + 63) / 64;                       // 64 rows per block
    const int gath_grid = (n * 64 + 255) / 256;            // one wave per node

    // layer 1 (fp32 input)
    gemm_mfma<128, false><<<ggemm, 256, 0, stream>>>(x, Wt1, nullptr, cnt, bufA, n);
    gather_kernel<128><<<gath_grid, 256, 0, stream>>>(bufA, cnt, bucket, bufB, n);
    // layer 2 (fp16 input)
    gemm_mfma<128, true><<<ggemm, 256, 0, stream>>>(bufB, Wt2, b1, cnt, bufA, n);
    gather_kernel<128><<<gath_grid, 256, 0, stream>>>(bufA, cnt, bucket, bufB, n);
    // layer 3 (64-wide, fp16 input)
    gemm_mfma<64, true><<<ggemm, 256, 0, stream>>>(bufB, Wt3, b2, cnt, bufA, n);
    // head: gather64 + relu(+b3) + mean-pool + MLP (last-block), one dispatch
    fused_gpool<<<2048, 256, 0, stream>>>(bufA, cnt, bucket, b3, batch, pooled,
                                          Wf1, bf1, Wf2, bf2, out, done, n);
}

// Round 16
// 278.405 us; speedup vs baseline: 2.6861x; 2.6861x over previous
//
#include <hip/hip_runtime.h>
#include <hip/hip_fp16.h>

// GCN: 3x (GEMM -> normalized adjacency aggregate) + mean-pool + MLP.
// R2 scatter->CSR+gather. R6 hs fp16 (419). R7 col-part fill (409).
// R8 fp16 MFMA GEMM (345). R9 pool split (341). R11 fp16 gather out (338).
// R14 fixed-capacity bucket fill; 9 dispatches (288).
// R15 REGRESSED (748): per-thread __threadfence (device scope, 8 XCDs -> L2
//   writeback) in last-block-MLP pattern serialized 8192 waves. Lesson: never
//   trade an 11us dispatch for a per-wave device fence.
// R16: exact R14 + ONLY the 2-half-wave-stream gpool gather (16 outstanding
//   row loads/wave, shfl^32 combine), separate mlp_kernel. 9 dispatches.
//   out[c] = dinv[c] * ( hs[c] + sum_{(r->c)} hs[r] ),  hs = (X@W) * dinv[row]

#define NGRAPH 100
#define CAP 64           // bucket slots per node

typedef _Float16 f16x8 __attribute__((ext_vector_type(8)));
typedef float f32x4 __attribute__((ext_vector_type(4)));

// ---------------- prep: Wt transpose-to-fp16 + zero cnt + zero pooled ----------------

__global__ __launch_bounds__(256) void prep_all(const float* __restrict__ W1,
                                                const float* __restrict__ W2,
                                                const float* __restrict__ W3,
                                                __half* __restrict__ Wt1,
                                                __half* __restrict__ Wt2,
                                                __half* __restrict__ Wt3,
                                                int* __restrict__ cnt,
                                                float* __restrict__ pooled, int n) {
    const int idx = blockIdx.x * 256 + threadIdx.x;    // 256 blocks = 65536 thr
    if (idx < 16384) {
        int nn = idx >> 7, k = idx & 127;
        Wt1[idx] = __float2half(W1[k * 128 + nn]);
    } else if (idx < 32768) {
        int j = idx - 16384;
        int nn = j >> 7, k = j & 127;
        Wt2[j] = __float2half(W2[k * 128 + nn]);
    } else if (idx < 40960) {
        int j = idx - 32768;
        int nn = j >> 7, k = j & 127;
        Wt3[j] = __float2half(W3[k * 64 + nn]);
    }
    if (idx < n) cnt[idx] = 0;                          // 65536 >= n
    if (idx < NGRAPH * 64) pooled[idx] = 0.0f;
}

// ---------------- bucket fill, col-partitioned (deg+scan+fill in one) ----------

__global__ void fill_bucket(const int* __restrict__ row, const int* __restrict__ col,
                            int* __restrict__ cnt, int* __restrict__ bucket,
                            int E, int colsPerGroup) {
    const int g  = blockIdx.x & 7;
    const int gb = blockIdx.x >> 3;
    const int nb = gridDim.x >> 3;
    const int lo = g * colsPerGroup, hi = lo + colsPerGroup;
    for (int e = gb * 256 + threadIdx.x; e < E; e += nb * 256) {
        int c = col[e];
        if (c >= lo && c < hi) {
            int pos = atomicAdd(&cnt[c], 1);
            bucket[c * CAP + pos] = row[e];
        }
    }
}

// ---------------- MFMA GEMM: Yh(fp16) = relu?(X + b) @ W * dinv[row] ----------

template <int OUT, bool F16IN>
__global__ __launch_bounds__(256) void gemm_mfma(const void* __restrict__ Xv,
                                                 const __half* __restrict__ Wt,
                                                 const float* __restrict__ bias_in,
                                                 const int* __restrict__ cnt,
                                                 __half* __restrict__ Yh, int n) {
    __shared__ _Float16 Xs[64 * 128];
    __shared__ _Float16 Ws[OUT * 128];
    __shared__ float bs[128];

    const float*  Xf = (const float*)Xv;
    const __half* Xh = (const __half*)Xv;

    const int t = threadIdx.x;
    if (t < 128) bs[t] = (bias_in != nullptr) ? bias_in[t] : 0.0f;
    __syncthreads();

    const int row0 = blockIdx.x * 64;
    const bool do_relu = (bias_in != nullptr);

    for (int c = t; c < 64 * 16; c += 256) {
        const int r = c >> 4, q = c & 15;
        const int gr = row0 + r;
        float vals[8];
        #pragma unroll
        for (int i = 0; i < 8; ++i) vals[i] = 0.0f;
        if (gr < n) {
            if (F16IN) {
                f16x8 hv = *(const f16x8*)&Xh[(size_t)gr * 128 + q * 8];
                #pragma unroll
                for (int i = 0; i < 8; ++i) vals[i] = (float)hv[i];
            } else {
                float4 va = *(const float4*)&Xf[(size_t)gr * 128 + q * 8];
                float4 vb = *(const float4*)&Xf[(size_t)gr * 128 + q * 8 + 4];
                vals[0] = va.x; vals[1] = va.y; vals[2] = va.z; vals[3] = va.w;
                vals[4] = vb.x; vals[5] = vb.y; vals[6] = vb.z; vals[7] = vb.w;
            }
        }
        if (do_relu) {
            const int k = q * 8;
            #pragma unroll
            for (int i = 0; i < 8; ++i) vals[i] = fmaxf(vals[i] + bs[k + i], 0.f);
        }
        f16x8 hv;
        #pragma unroll
        for (int i = 0; i < 8; ++i) hv[i] = (_Float16)vals[i];
        *(f16x8*)&Xs[(size_t)((r << 4) + (q ^ (r & 15))) * 8] = hv;
    }
    for (int c = t; c < OUT * 16; c += 256) {
        const int nn = c >> 4, q = c & 15;
        f16x8 w = *(const f16x8*)&Wt[nn * 128 + q * 8];
        *(f16x8*)&Ws[(size_t)((nn << 4) + (q ^ (nn & 15))) * 8] = w;
    }
    __syncthreads();

    constexpr int NT = OUT / 16;
    const int lane = t & 63, wave = t >> 6;
    const int m = lane & 15, quad = lane >> 4;

    f32x4 acc[NT];
    #pragma unroll
    for (int i = 0; i < NT; ++i) acc[i] = (f32x4){0.f, 0.f, 0.f, 0.f};

    #pragma unroll
    for (int s = 0; s < 4; ++s) {
        const int qa = s * 4 + quad;
        f16x8 a = *(const f16x8*)&Xs[(size_t)(((wave * 16 + m) << 4) + (qa ^ m)) * 8];
        #pragma unroll
        for (int tt = 0; tt < NT; ++tt) {
            f16x8 b = *(const f16x8*)&Ws[(size_t)(((tt * 16 + m) << 4) + (qa ^ m)) * 8];
            acc[tt] = __builtin_amdgcn_mfma_f32_16x16x32_f16(a, b, acc[tt], 0, 0, 0);
        }
    }

    #pragma unroll
    for (int i = 0; i < 4; ++i) {
        const int gr = row0 + wave * 16 + quad * 4 + i;
        if (gr < n) {
            const float dw = 1.0f / sqrtf((float)(cnt[gr] + 1));
            #pragma unroll
            for (int tt = 0; tt < NT; ++tt)
                Yh[(size_t)gr * OUT + tt * 16 + m] = __float2half(acc[tt][i] * dw);
        }
    }
}

// ---------------- gather<128> (bucket-based): fp16 in/out, fp32 accum ----------------

template <int F>
__global__ void gather_kernel(const __half* __restrict__ hs, const int* __restrict__ cnt,
                              const int* __restrict__ bucket,
                              __half* __restrict__ outh, int n) {
    const int lane = threadIdx.x & 63;
    const int c = (blockIdx.x * blockDim.x + threadIdx.x) >> 6;
    if (c >= n) return;
    const int beg = c * CAP;
    const int end = beg + cnt[c];
    const float w = 1.0f / sqrtf((float)(cnt[c] + 1));
    const float2* hq = (const float2*)hs;

    auto cvt = [](float2 raw) {
        __half2 ha = *(__half2*)&raw.x;
        __half2 hb = *(__half2*)&raw.y;
        float2 fa = __half22float2(ha);
        float2 fb = __half22float2(hb);
        return make_float4(fa.x, fa.y, fb.x, fb.y);
    };
    auto pack = [](float4 v) {
        float2 o;
        *(__half2*)&o.x = __float22half2_rn(make_float2(v.x, v.y));
        *(__half2*)&o.y = __float22half2_rn(make_float2(v.z, v.w));
        return o;
    };

    if (F == 128) {
        const int half = lane >> 5;
        const int l    = lane & 31;
        float4 acc = make_float4(0.f, 0.f, 0.f, 0.f);
        if (half == 0) acc = cvt(hq[(size_t)c * 32 + l]);
        int j = beg + half;
        for (; j + 6 < end; j += 8) {
            int s0 = bucket[j], s1 = bucket[j + 2], s2 = bucket[j + 4], s3 = bucket[j + 6];
            float4 v0 = cvt(hq[(size_t)s0 * 32 + l]);
            float4 v1 = cvt(hq[(size_t)s1 * 32 + l]);
            float4 v2 = cvt(hq[(size_t)s2 * 32 + l]);
            float4 v3 = cvt(hq[(size_t)s3 * 32 + l]);
            acc.x += v0.x + v1.x + v2.x + v3.x;
            acc.y += v0.y + v1.y + v2.y + v3.y;
            acc.z += v0.z + v1.z + v2.z + v3.z;
            acc.w += v0.w + v1.w + v2.w + v3.w;
        }
        for (; j < end; j += 2) {
            float4 v = cvt(hq[(size_t)bucket[j] * 32 + l]);
            acc.x += v.x; acc.y += v.y; acc.z += v.z; acc.w += v.w;
        }
        acc.x += __shfl(acc.x, lane ^ 32);
        acc.y += __shfl(acc.y, lane ^ 32);
        acc.z += __shfl(acc.z, lane ^ 32);
        acc.w += __shfl(acc.w, lane ^ 32);
        if (half == 0) {
            float4 o = make_float4(w * acc.x, w * acc.y, w * acc.z, w * acc.w);
            *(float2*)&outh[(size_t)c * 128 + l * 4] = pack(o);
        }
    }
}

// ---------------- fused gather(64) + pool: 2 half-wave edge streams ----------------
// 32 lanes x dword (2 fp16) = full 128B row per stream; 8-deep unroll per stream
// -> 16 outstanding row loads/wave. shfl^32 combine. Boundary-flush atomics
// (batch sorted -> wave-uniform). NO fences, NO last-block work (R15 lesson).

__global__ __launch_bounds__(256) void fused_gpool(const __half* __restrict__ hs,
                                                   const int* __restrict__ cnt,
                                                   const int* __restrict__ bucket,
                                                   const float* __restrict__ b3,
                                                   const int* __restrict__ batch,
                                                   float* __restrict__ pooled, int n) {
    const int lane  = threadIdx.x & 63;
    const int half  = lane >> 5;               // edge stream id
    const int li    = lane & 31;               // dword index in 64-feat row
    const int wave  = (blockIdx.x * blockDim.x + threadIdx.x) >> 6;
    const int nwav  = (gridDim.x * blockDim.x) >> 6;
    const int chunk = (n + nwav - 1) / nwav;
    const int beg = wave * chunk;
    const int end = min(beg + chunk, n);
    if (beg >= end) return;
    const unsigned* h2 = (const unsigned*)hs;  // row = 32 dwords

    auto cvt2 = [](unsigned raw) { return __half22float2(*(__half2*)&raw); };

    const float bias0 = b3[li * 2], bias1 = b3[li * 2 + 1];
    int curg = batch[beg];
    float2 acc = make_float2(0.f, 0.f);
    for (int i = beg; i < end; ++i) {
        int g = batch[i];                      // wave-uniform
        if (g != curg) {
            if (half == 0) {
                atomicAdd(&pooled[curg * 64 + li * 2],     acc.x);
                atomicAdd(&pooled[curg * 64 + li * 2 + 1], acc.y);
            }
            acc = make_float2(0.f, 0.f); curg = g;
        }
        const int deg = cnt[i];
        const float dv = 1.0f / sqrtf((float)(deg + 1));
        float2 sv = make_float2(0.f, 0.f);
        if (half == 0) sv = cvt2(h2[(size_t)i * 32 + li]);   // self-loop
        const int eb = i * CAP, ee = eb + deg;
        int j = eb + half;
        for (; j + 14 < ee; j += 16) {         // 8-deep per stream
            int a0 = bucket[j],      a1 = bucket[j + 2],  a2 = bucket[j + 4],  a3 = bucket[j + 6];
            int a4 = bucket[j + 8],  a5 = bucket[j + 10], a6 = bucket[j + 12], a7 = bucket[j + 14];
            float2 v0 = cvt2(h2[(size_t)a0 * 32 + li]);
            float2 v1 = cvt2(h2[(size_t)a1 * 32 + li]);
            float2 v2 = cvt2(h2[(size_t)a2 * 32 + li]);
            float2 v3 = cvt2(h2[(size_t)a3 * 32 + li]);
            float2 v4 = cvt2(h2[(size_t)a4 * 32 + li]);
            float2 v5 = cvt2(h2[(size_t)a5 * 32 + li]);
            float2 v6 = cvt2(h2[(size_t)a6 * 32 + li]);
            float2 v7 = cvt2(h2[(size_t)a7 * 32 + li]);
            sv.x += (v0.x + v1.x) + (v2.x + v3.x) + (v4.x + v5.x) + (v6.x + v7.x);
            sv.y += (v0.y + v1.y) + (v2.y + v3.y) + (v4.y + v5.y) + (v6.y + v7.y);
        }
        for (; j < ee; j += 2) {
            float2 v = cvt2(h2[(size_t)bucket[j] * 32 + li]);
            sv.x += v.x; sv.y += v.y;
        }
        sv.x += __shfl(sv.x, lane ^ 32);       // combine streams
        sv.y += __shfl(sv.y, lane ^ 32);
        acc.x += fmaxf(dv * sv.x + bias0, 0.f);
        acc.y += fmaxf(dv * sv.y + bias1, 0.f);
    }
    if (half == 0) {
        atomicAdd(&pooled[curg * 64 + li * 2],     acc.x);
        atomicAdd(&pooled[curg * 64 + li * 2 + 1], acc.y);
    }
}

// ---------------- mean + 64->32->10 MLP ----------------

__global__ __launch_bounds__(64) void mlp_kernel(const float* __restrict__ pooled,
                                                 const int* __restrict__ batch,
                                                 const float* __restrict__ Wf1,
                                                 const float* __restrict__ bf1,
                                                 const float* __restrict__ Wf2,
                                                 const float* __restrict__ bf2,
                                                 float* __restrict__ out, int n) {
    const int g = blockIdx.x;
    const int t = threadIdx.x;

    auto lb = [&](int v) {
        int lo = 0, hi = n;
        while (lo < hi) { int mid = (lo + hi) >> 1; if (batch[mid] < v) lo = mid + 1; else hi = mid; }
        return lo;
    };
    const int cnt = lb(g + 1) - lb(g);

    __shared__ float pm[64];
    __shared__ float hid[32];

    pm[t] = pooled[g * 64 + t] / (float)(cnt > 0 ? cnt : 1);
    __syncthreads();

    if (t < 32) {
        float a = bf1[t];
        #pragma unroll
        for (int k = 0; k < 64; ++k) a += pm[k] * Wf1[k * 32 + t];
        hid[t] = fmaxf(a, 0.f);
    }
    __syncthreads();

    if (t < 10) {
        float a = bf2[t];
        #pragma unroll
        for (int k = 0; k < 32; ++k) a += hid[k] * Wf2[k * 10 + t];
        out[g * 10 + t] = a;
    }
}

// ---------------- launcher ----------------

extern "C" void kernel_launch(void* const* d_in, const int* in_sizes, int n_in,
                              void* d_out, int out_size, void* d_ws, size_t ws_size,
                              hipStream_t stream) {
    const float* x     = (const float*)d_in[0];
    const int*   edge  = (const int*)  d_in[1];
    const int*   batch = (const int*)  d_in[2];
    const float* W1    = (const float*)d_in[3];
    const float* b1    = (const float*)d_in[4];
    const float* W2    = (const float*)d_in[5];
    const float* b2    = (const float*)d_in[6];
    const float* W3    = (const float*)d_in[7];
    const float* b3    = (const float*)d_in[8];
    const float* Wf1   = (const float*)d_in[9];
    const float* bf1   = (const float*)d_in[10];
    const float* Wf2   = (const float*)d_in[11];
    const float* bf2   = (const float*)d_in[12];
    float* out = (float*)d_out;

    const int E = in_sizes[1] / 2;     // 800000
    const int n = in_sizes[2];         // 50000
    const int* row = edge;
    const int* col = edge + E;

    const int colsPerGroup = (n + 7) / 8;                  // 6250

    const size_t n_pad = ((size_t)n + 64) & ~(size_t)63;
    char* wsb = (char*)d_ws;
    int*    cnt    = (int*)wsb;                  wsb += n_pad * 4;            // degree
    float*  pooled = (float*)wsb;                wsb += NGRAPH * 64 * 4;
    int*    bucket = (int*)wsb;                  wsb += (size_t)n_pad * CAP * 4;  // 12.8 MB
    __half* Wt1    = (__half*)wsb;               wsb += 16384 * 2;
    __half* Wt2    = (__half*)wsb;               wsb += 16384 * 2;
    __half* Wt3    = (__half*)wsb;               wsb += 8192 * 2;
    __half* bufA   = (__half*)wsb;               wsb += (size_t)n * 128 * 2;  // 12.8 MB
    __half* bufB   = (__half*)wsb;                                            // 12.8 MB

    // ---- prep + bucket build ----
    prep_all<<<256, 256, 0, stream>>>(W1, W2, W3, Wt1, Wt2, Wt3, cnt, pooled, n);
    fill_bucket<<<1024, 256, 0, stream>>>(row, col, cnt, bucket, E, colsPerGroup);

    const int ggemm = (n + 63) / 64;                       // 64 rows per block
    const int gath_grid = (n * 64 + 255) / 256;            // one wave per node

    // layer 1 (fp32 input)
    gemm_mfma<128, false><<<ggemm, 256, 0, stream>>>(x, Wt1, nullptr, cnt, bufA, n);
    gather_kernel<128><<<gath_grid, 256, 0, stream>>>(bufA, cnt, bucket, bufB, n);
    // layer 2 (fp16 input)
    gemm_mfma<128, true><<<ggemm, 256, 0, stream>>>(bufB, Wt2, b1, cnt, bufA, n);
    gather_kernel<128><<<gath_grid, 256, 0, stream>>>(bufA, cnt, bucket, bufB, n);
    // layer 3 (64-wide, fp16 input)
    gemm_mfma<64, true><<<ggemm, 256, 0, stream>>>(bufB, Wt3, b2, cnt, bufA, n);
    // head: gather64 + relu(+b3) + mean-pool fused; then MLP
    fused_gpool<<<2048, 256, 0, stream>>>(bufA, cnt, bucket, b3, batch, pooled, n);
    mlp_kernel<<<NGRAPH, 64, 0, stream>>>(pooled, batch, Wf1, bf1, Wf2, bf2, out, n);
}